// Round 1
// baseline (369.929 us; speedup 1.0000x reference)
//
#include <hip/hip_runtime.h>
#include <math.h>

// ---------------------------------------------------------------------------
// Mamba block forward, fp32, chunked-scan formulation.
// B=8, L=4096, D_MODEL=64, D_INNER=256, D_STATE=16, DT_RANK=4, D_CONV=4
// ---------------------------------------------------------------------------

constexpr int BATCH = 8;
constexpr int LEN   = 4096;
constexpr int DM    = 64;
constexpr int DI    = 256;
constexpr int DS    = 16;
constexpr int ROWS  = BATCH * LEN;   // 32768
constexpr int CH    = 64;            // scan chunk length
constexpr int NCH   = LEN / CH;      // 64 chunks

static __device__ __forceinline__ float sigmoidf_fast(float x) {
  return 1.0f / (1.0f + __expf(-x));
}
static __device__ __forceinline__ float softplusf_acc(float x) {
  // stable softplus, matches log1p(exp(x))
  return fmaxf(x, 0.0f) + log1pf(expf(-fabsf(x)));
}

// ---------------------------------------------------------------------------
// K1: xz = x @ W_in^T  (M=32768, N=512, K=64), split into xs (first 256 cols)
// and z (last 256 cols). 64x64 tile per block, K=64 fully resident in LDS.
// LDS layout transposed ([k][m]) so inner-loop reads are ds_read_b128.
// ---------------------------------------------------------------------------
__global__ __launch_bounds__(256) void k_xz(const float* __restrict__ x,
                                            const float* __restrict__ Win,
                                            float* __restrict__ xs,
                                            float* __restrict__ z) {
  __shared__ float Xs[64][64];  // [k][m]
  __shared__ float Ws[64][64];  // [k][e]
  const int t  = threadIdx.x;
  const int m0 = blockIdx.x * 64;
  const int e0 = blockIdx.y * 64;

  {
    const int r  = t >> 2;           // 0..63 (tile row)
    const int kc = (t & 3) * 16;     // k chunk base
    const float4* xp = reinterpret_cast<const float4*>(x   + (m0 + r) * DM + kc);
    const float4* wp = reinterpret_cast<const float4*>(Win + (e0 + r) * DM + kc);
#pragma unroll
    for (int i = 0; i < 4; ++i) {
      float4 a = xp[i];
      float4 w = wp[i];
      const int k = kc + i * 4;
      Xs[k + 0][r] = a.x; Xs[k + 1][r] = a.y; Xs[k + 2][r] = a.z; Xs[k + 3][r] = a.w;
      Ws[k + 0][r] = w.x; Ws[k + 1][r] = w.y; Ws[k + 2][r] = w.z; Ws[k + 3][r] = w.w;
    }
  }
  __syncthreads();

  const int tx = t & 15, ty = t >> 4;
  float acc[4][4] = {};
#pragma unroll 4
  for (int k = 0; k < 64; ++k) {
    const float4 av = *reinterpret_cast<const float4*>(&Xs[k][ty * 4]);
    const float4 bv = *reinterpret_cast<const float4*>(&Ws[k][tx * 4]);
    const float a[4] = {av.x, av.y, av.z, av.w};
    const float b[4] = {bv.x, bv.y, bv.z, bv.w};
#pragma unroll
    for (int i = 0; i < 4; ++i)
#pragma unroll
      for (int j = 0; j < 4; ++j) acc[i][j] = fmaf(a[i], b[j], acc[i][j]);
  }

  float* dst;
  int col;
  if (e0 < DI) { dst = xs; col = e0; } else { dst = z; col = e0 - DI; }
#pragma unroll
  for (int i = 0; i < 4; ++i) {
    float4 v = make_float4(acc[i][0], acc[i][1], acc[i][2], acc[i][3]);
    *reinterpret_cast<float4*>(dst + (m0 + ty * 4 + i) * DI + col + tx * 4) = v;
  }
}

// ---------------------------------------------------------------------------
// K2: depthwise causal conv (width 4) + bias + SiLU -> u
// One block per row (b,l); thread d handles one channel.
// ---------------------------------------------------------------------------
__global__ __launch_bounds__(256) void k_conv(const float* __restrict__ xs,
                                              const float* __restrict__ cw,
                                              const float* __restrict__ cb,
                                              float* __restrict__ u) {
  const int idx = blockIdx.x * 256 + threadIdx.x;
  const int d   = idx & (DI - 1);
  const int row = idx >> 8;
  const int l   = row & (LEN - 1);

  const float4 w = reinterpret_cast<const float4*>(cw)[d];
  const float wk[4] = {w.x, w.y, w.z, w.w};
  float acc = cb[d];
#pragma unroll
  for (int k = 0; k < 4; ++k) {
    const int ls = l - 3 + k;
    if (ls >= 0) acc = fmaf(xs[(row - 3 + k) * DI + d], wk[k], acc);
  }
  u[idx] = acc * sigmoidf_fast(acc);  // silu
}

// ---------------------------------------------------------------------------
// K3: dbc = u @ W_x^T (36 outs), dt = softplus(dbc[:4] @ W_dt^T + b_dt).
// One wave per row. W_x staged in LDS; u row staged in LDS per wave.
// ---------------------------------------------------------------------------
__global__ __launch_bounds__(256) void k_dbc(const float* __restrict__ u,
                                             const float* __restrict__ Wx,
                                             const float* __restrict__ Wdt,
                                             const float* __restrict__ bdt,
                                             float* __restrict__ dt,
                                             float* __restrict__ Bm,
                                             float* __restrict__ Cm) {
  __shared__ float Wxl[36][260];   // padded rows; 16B-aligned row stride
  __shared__ float urow[4][256];   // per-wave u row
  const int t = threadIdx.x;
  for (int i = t; i < 36 * 256; i += 256) Wxl[i >> 8][i & 255] = Wx[i];
  __syncthreads();

  const int wave = t >> 6, lane = t & 63;
#pragma unroll 1
  for (int it = 0; it < 4; ++it) {
    const int row = it * 8192 + blockIdx.x * 4 + wave;
    const float4 uv = reinterpret_cast<const float4*>(u + row * DI)[lane];
    reinterpret_cast<float4*>(&urow[wave][0])[lane] = uv;

    float s = 0.0f;
    if (lane < 36) {
      const float4* wr = reinterpret_cast<const float4*>(&Wxl[lane][0]);
      const float4* ur = reinterpret_cast<const float4*>(&urow[wave][0]);
#pragma unroll 8
      for (int e4 = 0; e4 < 64; ++e4) {
        const float4 wv = wr[e4];
        const float4 uu = ur[e4];
        s = fmaf(wv.x, uu.x, s);
        s = fmaf(wv.y, uu.y, s);
        s = fmaf(wv.z, uu.z, s);
        s = fmaf(wv.w, uu.w, s);
      }
    }
    // broadcast dt_raw (dbc[0..3]) to all lanes
    const float d0 = __shfl(s, 0), d1 = __shfl(s, 1), d2 = __shfl(s, 2), d3 = __shfl(s, 3);

    float4 o;
    float* op = &o.x;
#pragma unroll
    for (int q = 0; q < 4; ++q) {
      const int dd = lane * 4 + q;
      const float4 wv = reinterpret_cast<const float4*>(Wdt)[dd];
      const float v  = fmaf(d0, wv.x, fmaf(d1, wv.y, fmaf(d2, wv.z, fmaf(d3, wv.w, bdt[dd]))));
      op[q] = softplusf_acc(v);
    }
    reinterpret_cast<float4*>(dt + row * DI)[lane] = o;

    if (lane >= 4 && lane < 20)  Bm[row * DS + lane - 4]  = s;
    if (lane >= 20 && lane < 36) Cm[row * DS + lane - 20] = s;
  }
}

// ---------------------------------------------------------------------------
// K4a: per-chunk local scan (h starts at 0). Emits end-state and chunk dt-sum.
// Block = 256 threads = all d for one (b, chunk). H layout: [b][c][n][d].
// ---------------------------------------------------------------------------
__global__ __launch_bounds__(256) void k_scanA(const float* __restrict__ dt,
                                               const float* __restrict__ u,
                                               const float* __restrict__ Bm,
                                               const float* __restrict__ Alog,
                                               float* __restrict__ H,
                                               float* __restrict__ DTS) {
  const int d   = threadIdx.x;
  const int blk = blockIdx.x;           // b*NCH + c
  const int c   = blk & (NCH - 1);
  const int b   = blk >> 6;

  float A[DS];
#pragma unroll
  for (int n = 0; n < DS; ++n) A[n] = -expf(Alog[d * DS + n]);

  float h[DS] = {};
  float dts = 0.0f;
  const int base = b * LEN + c * CH;
#pragma unroll 1
  for (int s = 0; s < CH; ++s) {
    const int row = base + s;
    const float dtv = dt[row * DI + d];
    const float uv  = u[row * DI + d];
    const float du  = dtv * uv;
    float Bv[16];
    const float4* Bp = reinterpret_cast<const float4*>(Bm + row * DS);
    *reinterpret_cast<float4*>(&Bv[0])  = Bp[0];
    *reinterpret_cast<float4*>(&Bv[4])  = Bp[1];
    *reinterpret_cast<float4*>(&Bv[8])  = Bp[2];
    *reinterpret_cast<float4*>(&Bv[12]) = Bp[3];
    dts += dtv;
#pragma unroll
    for (int n = 0; n < DS; ++n)
      h[n] = fmaf(h[n], __expf(dtv * A[n]), du * Bv[n]);
  }
#pragma unroll
  for (int n = 0; n < DS; ++n) H[(blk * DS + n) * DI + d] = h[n];
  DTS[blk * DI + d] = dts;
}

// ---------------------------------------------------------------------------
// K4b: stitch chunks. h_true[c] = h_local[c] + exp(A * dtsum[c]) * h_true[c-1]
// One thread per (b,d,n); 64 sequential chunk steps. H updated in place.
// ---------------------------------------------------------------------------
__global__ __launch_bounds__(256) void k_fix(float* __restrict__ H,
                                             const float* __restrict__ DTS,
                                             const float* __restrict__ Alog) {
  const int tid = blockIdx.x * 256 + threadIdx.x;  // 32768
  const int d = tid & (DI - 1);
  const int n = (tid >> 8) & (DS - 1);
  const int b = tid >> 12;
  const float A = -expf(Alog[d * DS + n]);
  float h = 0.0f;
#pragma unroll 1
  for (int c = 0; c < NCH; ++c) {
    const int bc  = b * NCH + c;
    const float P = __expf(A * DTS[bc * DI + d]);
    const int idx = (bc * DS + n) * DI + d;
    h = fmaf(P, h, H[idx]);
    H[idx] = h;
  }
}

// ---------------------------------------------------------------------------
// K4c: re-run each chunk from its true incoming state; compute y, add u*D,
// gate with silu(z), write gated y (over the z buffer).
// ---------------------------------------------------------------------------
__global__ __launch_bounds__(256) void k_scanC(const float* __restrict__ dt,
                                               const float* __restrict__ u,
                                               const float* __restrict__ zg,
                                               const float* __restrict__ Bm,
                                               const float* __restrict__ Cm,
                                               const float* __restrict__ Alog,
                                               const float* __restrict__ Dp,
                                               const float* __restrict__ H,
                                               float* __restrict__ yg) {
  const int d   = threadIdx.x;
  const int blk = blockIdx.x;
  const int c   = blk & (NCH - 1);
  const int b   = blk >> 6;

  float A[DS];
#pragma unroll
  for (int n = 0; n < DS; ++n) A[n] = -expf(Alog[d * DS + n]);

  float h[DS];
  if (c > 0) {
#pragma unroll
    for (int n = 0; n < DS; ++n) h[n] = H[((blk - 1) * DS + n) * DI + d];
  } else {
#pragma unroll
    for (int n = 0; n < DS; ++n) h[n] = 0.0f;
  }

  const float Dpd = Dp[d];
  const int base = b * LEN + c * CH;
#pragma unroll 1
  for (int s = 0; s < CH; ++s) {
    const int row = base + s;
    const float dtv = dt[row * DI + d];
    const float uv  = u[row * DI + d];
    const float zv  = zg[row * DI + d];
    const float du  = dtv * uv;
    float Bv[16], Cv[16];
    const float4* Bp = reinterpret_cast<const float4*>(Bm + row * DS);
    const float4* Cp = reinterpret_cast<const float4*>(Cm + row * DS);
    *reinterpret_cast<float4*>(&Bv[0])  = Bp[0];
    *reinterpret_cast<float4*>(&Bv[4])  = Bp[1];
    *reinterpret_cast<float4*>(&Bv[8])  = Bp[2];
    *reinterpret_cast<float4*>(&Bv[12]) = Bp[3];
    *reinterpret_cast<float4*>(&Cv[0])  = Cp[0];
    *reinterpret_cast<float4*>(&Cv[4])  = Cp[1];
    *reinterpret_cast<float4*>(&Cv[8])  = Cp[2];
    *reinterpret_cast<float4*>(&Cv[12]) = Cp[3];

    float y = 0.0f;
#pragma unroll
    for (int n = 0; n < DS; ++n) {
      h[n] = fmaf(h[n], __expf(dtv * A[n]), du * Bv[n]);
      y = fmaf(h[n], Cv[n], y);
    }
    const float yv = fmaf(uv, Dpd, y);
    yg[row * DI + d] = yv * zv * sigmoidf_fast(zv);
  }
}

// ---------------------------------------------------------------------------
// K5: out = yg @ W_out^T (M=32768, N=64, K=256). W_out^T staged in LDS (64KB).
// One wave processes 4 rows to amortize LDS reads; lane j owns output col j.
// ---------------------------------------------------------------------------
__global__ __launch_bounds__(256) void k_out(const float* __restrict__ yg,
                                             const float* __restrict__ Wout,
                                             float* __restrict__ out) {
  __shared__ float WT[DI * DM];  // [k][j], 64 KB
  const int t = threadIdx.x;
  {
    const int j  = t & 63;
    const int kq = (t >> 6) * 4;
#pragma unroll
    for (int ch = 0; ch < 16; ++ch) {
      const int k0 = ch * 16 + kq;
      const float4 w = *reinterpret_cast<const float4*>(Wout + j * DI + k0);
      WT[(k0 + 0) * DM + j] = w.x;
      WT[(k0 + 1) * DM + j] = w.y;
      WT[(k0 + 2) * DM + j] = w.z;
      WT[(k0 + 3) * DM + j] = w.w;
    }
  }
  __syncthreads();

  const int wave = t >> 6, lane = t & 63;
  const int r0 = (blockIdx.x * 4 + wave) * 4;
  float a0 = 0.f, a1 = 0.f, a2 = 0.f, a3 = 0.f;
  const float* y0 = yg + (r0 + 0) * DI;
  const float* y1 = yg + (r0 + 1) * DI;
  const float* y2 = yg + (r0 + 2) * DI;
  const float* y3 = yg + (r0 + 3) * DI;
#pragma unroll 4
  for (int k = 0; k < DI; ++k) {
    const float wv = WT[k * DM + lane];
    a0 = fmaf(y0[k], wv, a0);
    a1 = fmaf(y1[k], wv, a1);
    a2 = fmaf(y2[k], wv, a2);
    a3 = fmaf(y3[k], wv, a3);
  }
  out[(r0 + 0) * DM + lane] = a0;
  out[(r0 + 1) * DM + lane] = a1;
  out[(r0 + 2) * DM + lane] = a2;
  out[(r0 + 3) * DM + lane] = a3;
}

// ---------------------------------------------------------------------------
extern "C" void kernel_launch(void* const* d_in, const int* in_sizes, int n_in,
                              void* d_out, int out_size, void* d_ws, size_t ws_size,
                              hipStream_t stream) {
  const float* x    = (const float*)d_in[0];
  const float* Win  = (const float*)d_in[1];
  const float* cw   = (const float*)d_in[2];
  const float* cb   = (const float*)d_in[3];
  const float* Wx   = (const float*)d_in[4];
  const float* Wdt  = (const float*)d_in[5];
  const float* bdt  = (const float*)d_in[6];
  const float* Alog = (const float*)d_in[7];
  const float* Dp   = (const float*)d_in[8];
  const float* Wout = (const float*)d_in[9];
  float* out = (float*)d_out;

  // workspace layout (floats)
  float* ws  = (float*)d_ws;
  float* xs  = ws;                                   // ROWS*DI
  float* z   = xs  + (size_t)ROWS * DI;              // ROWS*DI (later: gated y)
  float* u   = z   + (size_t)ROWS * DI;              // ROWS*DI
  float* dtb = u   + (size_t)ROWS * DI;              // ROWS*DI
  float* Bm  = dtb + (size_t)ROWS * DI;              // ROWS*DS
  float* Cm  = Bm  + (size_t)ROWS * DS;              // ROWS*DS
  float* H   = Cm  + (size_t)ROWS * DS;              // BATCH*NCH*DS*DI
  float* DTS = H   + (size_t)BATCH * NCH * DS * DI;  // BATCH*NCH*DI
  // total ~147.3 MB

  k_xz   <<<dim3(ROWS / 64, 8), 256, 0, stream>>>(x, Win, xs, z);
  k_conv <<<ROWS * DI / 256, 256, 0, stream>>>(xs, cw, cb, u);
  k_dbc  <<<2048, 256, 0, stream>>>(u, Wx, Wdt, bdt, dtb, Bm, Cm);
  k_scanA<<<BATCH * NCH, 256, 0, stream>>>(dtb, u, Bm, Alog, H, DTS);
  k_fix  <<<BATCH * DI * DS / 256, 256, 0, stream>>>(H, DTS, Alog);
  k_scanC<<<BATCH * NCH, 256, 0, stream>>>(dtb, u, z, Bm, Cm, Alog, Dp, H, z);
  k_out  <<<ROWS / 16, 256, 0, stream>>>(z, Wout, out);
}

// Round 5
// 309.612 us; speedup vs baseline: 1.1948x; 1.1948x over previous
//
#include <hip/hip_runtime.h>
#include <math.h>

// ---------------------------------------------------------------------------
// Mamba block forward, fp32, chunked-scan formulation.
// B=8, L=4096, D_MODEL=64, D_INNER=256, D_STATE=16, DT_RANK=4, D_CONV=4
// ---------------------------------------------------------------------------

constexpr int BATCH = 8;
constexpr int LEN   = 4096;
constexpr int DM    = 64;
constexpr int DI    = 256;
constexpr int DS    = 16;
constexpr int ROWS  = BATCH * LEN;   // 32768
constexpr int CH    = 64;            // scan chunk length
constexpr int NCH   = LEN / CH;      // 64 chunks

static __device__ __forceinline__ float sigmoidf_fast(float x) {
  return 1.0f / (1.0f + __expf(-x));
}
static __device__ __forceinline__ float softplusf_acc(float x) {
  // stable softplus, matches log1p(exp(x))
  return fmaxf(x, 0.0f) + log1pf(expf(-fabsf(x)));
}

// ---------------------------------------------------------------------------
// K1: xz = x @ W_in^T  (M=32768, N=512, K=64), split into xs (first 256 cols)
// and z (last 256 cols). 64x64 tile per block, K=64 fully resident in LDS.
// LDS layout transposed ([k][m]) so inner-loop reads are ds_read_b128.
// ---------------------------------------------------------------------------
__global__ __launch_bounds__(256) void k_xz(const float* __restrict__ x,
                                            const float* __restrict__ Win,
                                            float* __restrict__ xs,
                                            float* __restrict__ z) {
  __shared__ float Xs[64][64];  // [k][m]
  __shared__ float Ws[64][64];  // [k][e]
  const int t  = threadIdx.x;
  const int m0 = blockIdx.x * 64;
  const int e0 = blockIdx.y * 64;

  {
    const int r  = t >> 2;           // 0..63 (tile row)
    const int kc = (t & 3) * 16;     // k chunk base
    const float4* xp = reinterpret_cast<const float4*>(x   + (m0 + r) * DM + kc);
    const float4* wp = reinterpret_cast<const float4*>(Win + (e0 + r) * DM + kc);
#pragma unroll
    for (int i = 0; i < 4; ++i) {
      float4 a = xp[i];
      float4 w = wp[i];
      const int k = kc + i * 4;
      Xs[k + 0][r] = a.x; Xs[k + 1][r] = a.y; Xs[k + 2][r] = a.z; Xs[k + 3][r] = a.w;
      Ws[k + 0][r] = w.x; Ws[k + 1][r] = w.y; Ws[k + 2][r] = w.z; Ws[k + 3][r] = w.w;
    }
  }
  __syncthreads();

  const int tx = t & 15, ty = t >> 4;
  float acc[4][4] = {};
#pragma unroll 4
  for (int k = 0; k < 64; ++k) {
    const float4 av = *reinterpret_cast<const float4*>(&Xs[k][ty * 4]);
    const float4 bv = *reinterpret_cast<const float4*>(&Ws[k][tx * 4]);
    const float a[4] = {av.x, av.y, av.z, av.w};
    const float b[4] = {bv.x, bv.y, bv.z, bv.w};
#pragma unroll
    for (int i = 0; i < 4; ++i)
#pragma unroll
      for (int j = 0; j < 4; ++j) acc[i][j] = fmaf(a[i], b[j], acc[i][j]);
  }

  float* dst;
  int col;
  if (e0 < DI) { dst = xs; col = e0; } else { dst = z; col = e0 - DI; }
#pragma unroll
  for (int i = 0; i < 4; ++i) {
    float4 v = make_float4(acc[i][0], acc[i][1], acc[i][2], acc[i][3]);
    *reinterpret_cast<float4*>(dst + (m0 + ty * 4 + i) * DI + col + tx * 4) = v;
  }
}

// ---------------------------------------------------------------------------
// K2: depthwise causal conv (width 4) + bias + SiLU -> u
// One block per row (b,l); thread d handles one channel.
// ---------------------------------------------------------------------------
__global__ __launch_bounds__(256) void k_conv(const float* __restrict__ xs,
                                              const float* __restrict__ cw,
                                              const float* __restrict__ cb,
                                              float* __restrict__ u) {
  const int idx = blockIdx.x * 256 + threadIdx.x;
  const int d   = idx & (DI - 1);
  const int row = idx >> 8;
  const int l   = row & (LEN - 1);

  const float4 w = reinterpret_cast<const float4*>(cw)[d];
  const float wk[4] = {w.x, w.y, w.z, w.w};
  float acc = cb[d];
#pragma unroll
  for (int k = 0; k < 4; ++k) {
    const int ls = l - 3 + k;
    if (ls >= 0) acc = fmaf(xs[(row - 3 + k) * DI + d], wk[k], acc);
  }
  u[idx] = acc * sigmoidf_fast(acc);  // silu
}

// ---------------------------------------------------------------------------
// K3: dbc = u @ W_x^T (36 outs), dt = softplus(dbc[:4] @ W_dt^T + b_dt).
// One wave per row. W_x staged in LDS; u row staged in LDS per wave.
// ---------------------------------------------------------------------------
__global__ __launch_bounds__(256) void k_dbc(const float* __restrict__ u,
                                             const float* __restrict__ Wx,
                                             const float* __restrict__ Wdt,
                                             const float* __restrict__ bdt,
                                             float* __restrict__ dt,
                                             float* __restrict__ Bm,
                                             float* __restrict__ Cm) {
  __shared__ float Wxl[36][260];   // padded rows; 16B-aligned row stride
  __shared__ float urow[4][256];   // per-wave u row
  const int t = threadIdx.x;
  for (int i = t; i < 36 * 256; i += 256) Wxl[i >> 8][i & 255] = Wx[i];
  __syncthreads();

  const int wave = t >> 6, lane = t & 63;
#pragma unroll 1
  for (int it = 0; it < 4; ++it) {
    const int row = it * 8192 + blockIdx.x * 4 + wave;
    const float4 uv = reinterpret_cast<const float4*>(u + row * DI)[lane];
    reinterpret_cast<float4*>(&urow[wave][0])[lane] = uv;

    float s = 0.0f;
    if (lane < 36) {
      const float4* wr = reinterpret_cast<const float4*>(&Wxl[lane][0]);
      const float4* ur = reinterpret_cast<const float4*>(&urow[wave][0]);
#pragma unroll 8
      for (int e4 = 0; e4 < 64; ++e4) {
        const float4 wv = wr[e4];
        const float4 uu = ur[e4];
        s = fmaf(wv.x, uu.x, s);
        s = fmaf(wv.y, uu.y, s);
        s = fmaf(wv.z, uu.z, s);
        s = fmaf(wv.w, uu.w, s);
      }
    }
    // broadcast dt_raw (dbc[0..3]) to all lanes
    const float d0 = __shfl(s, 0), d1 = __shfl(s, 1), d2 = __shfl(s, 2), d3 = __shfl(s, 3);

    float4 o;
    float* op = &o.x;
#pragma unroll
    for (int q = 0; q < 4; ++q) {
      const int dd = lane * 4 + q;
      const float4 wv = reinterpret_cast<const float4*>(Wdt)[dd];
      const float v  = fmaf(d0, wv.x, fmaf(d1, wv.y, fmaf(d2, wv.z, fmaf(d3, wv.w, bdt[dd]))));
      op[q] = softplusf_acc(v);
    }
    reinterpret_cast<float4*>(dt + row * DI)[lane] = o;

    if (lane >= 4 && lane < 20)  Bm[row * DS + lane - 4]  = s;
    if (lane >= 20 && lane < 36) Cm[row * DS + lane - 20] = s;
  }
}

// ---------------------------------------------------------------------------
// K4a: per-chunk local scan (h starts at 0). Emits end-state and chunk dt-sum.
// Block = 256 threads = all d for one (b, chunk). H layout: [b][c][n][d].
// ---------------------------------------------------------------------------
__global__ __launch_bounds__(256) void k_scanA(const float* __restrict__ dt,
                                               const float* __restrict__ u,
                                               const float* __restrict__ Bm,
                                               const float* __restrict__ Alog,
                                               float* __restrict__ H,
                                               float* __restrict__ DTS) {
  const int d   = threadIdx.x;
  const int blk = blockIdx.x;           // b*NCH + c
  const int c   = blk & (NCH - 1);
  const int b   = blk >> 6;

  float A[DS];
#pragma unroll
  for (int n = 0; n < DS; ++n) A[n] = -expf(Alog[d * DS + n]);

  float h[DS] = {};
  float dts = 0.0f;
  const int base = b * LEN + c * CH;
#pragma unroll 1
  for (int s = 0; s < CH; ++s) {
    const int row = base + s;
    const float dtv = dt[row * DI + d];
    const float uv  = u[row * DI + d];
    const float du  = dtv * uv;
    float Bv[16];
    const float4* Bp = reinterpret_cast<const float4*>(Bm + row * DS);
    *reinterpret_cast<float4*>(&Bv[0])  = Bp[0];
    *reinterpret_cast<float4*>(&Bv[4])  = Bp[1];
    *reinterpret_cast<float4*>(&Bv[8])  = Bp[2];
    *reinterpret_cast<float4*>(&Bv[12]) = Bp[3];
    dts += dtv;
#pragma unroll
    for (int n = 0; n < DS; ++n)
      h[n] = fmaf(h[n], __expf(dtv * A[n]), du * Bv[n]);
  }
#pragma unroll
  for (int n = 0; n < DS; ++n) H[(blk * DS + n) * DI + d] = h[n];
  DTS[blk * DI + d] = dts;
}

// ---------------------------------------------------------------------------
// K4b: stitch chunks. h_true[c] = h_local[c] + exp(A * dtsum[c]) * h_true[c-1]
// One thread per (b,d,n); 64 sequential chunk steps. H updated in place.
// ---------------------------------------------------------------------------
__global__ __launch_bounds__(256) void k_fix(float* __restrict__ H,
                                             const float* __restrict__ DTS,
                                             const float* __restrict__ Alog) {
  const int tid = blockIdx.x * 256 + threadIdx.x;  // 32768
  const int d = tid & (DI - 1);
  const int n = (tid >> 8) & (DS - 1);
  const int b = tid >> 12;
  const float A = -expf(Alog[d * DS + n]);
  float h = 0.0f;
#pragma unroll 1
  for (int c = 0; c < NCH; ++c) {
    const int bc  = b * NCH + c;
    const float P = __expf(A * DTS[bc * DI + d]);
    const int idx = (bc * DS + n) * DI + d;
    h = fmaf(P, h, H[idx]);
    H[idx] = h;
  }
}

// ---------------------------------------------------------------------------
// K4c: re-run each chunk from its true incoming state; compute y, add u*D,
// gate with silu(z), write gated y (over the z buffer).
// ---------------------------------------------------------------------------
__global__ __launch_bounds__(256) void k_scanC(const float* __restrict__ dt,
                                               const float* __restrict__ u,
                                               const float* __restrict__ zg,
                                               const float* __restrict__ Bm,
                                               const float* __restrict__ Cm,
                                               const float* __restrict__ Alog,
                                               const float* __restrict__ Dp,
                                               const float* __restrict__ H,
                                               float* __restrict__ yg) {
  const int d   = threadIdx.x;
  const int blk = blockIdx.x;
  const int c   = blk & (NCH - 1);
  const int b   = blk >> 6;

  float A[DS];
#pragma unroll
  for (int n = 0; n < DS; ++n) A[n] = -expf(Alog[d * DS + n]);

  float h[DS];
  if (c > 0) {
#pragma unroll
    for (int n = 0; n < DS; ++n) h[n] = H[((blk - 1) * DS + n) * DI + d];
  } else {
#pragma unroll
    for (int n = 0; n < DS; ++n) h[n] = 0.0f;
  }

  const float Dpd = Dp[d];
  const int base = b * LEN + c * CH;
#pragma unroll 1
  for (int s = 0; s < CH; ++s) {
    const int row = base + s;
    const float dtv = dt[row * DI + d];
    const float uv  = u[row * DI + d];
    const float zv  = zg[row * DI + d];
    const float du  = dtv * uv;
    float Bv[16], Cv[16];
    const float4* Bp = reinterpret_cast<const float4*>(Bm + row * DS);
    const float4* Cp = reinterpret_cast<const float4*>(Cm + row * DS);
    *reinterpret_cast<float4*>(&Bv[0])  = Bp[0];
    *reinterpret_cast<float4*>(&Bv[4])  = Bp[1];
    *reinterpret_cast<float4*>(&Bv[8])  = Bp[2];
    *reinterpret_cast<float4*>(&Bv[12]) = Bp[3];
    *reinterpret_cast<float4*>(&Cv[0])  = Cp[0];
    *reinterpret_cast<float4*>(&Cv[4])  = Cp[1];
    *reinterpret_cast<float4*>(&Cv[8])  = Cp[2];
    *reinterpret_cast<float4*>(&Cv[12]) = Cp[3];

    float y = 0.0f;
#pragma unroll
    for (int n = 0; n < DS; ++n) {
      h[n] = fmaf(h[n], __expf(dtv * A[n]), du * Bv[n]);
      y = fmaf(h[n], Cv[n], y);
    }
    const float yv = fmaf(uv, Dpd, y);
    yg[row * DI + d] = yv * zv * sigmoidf_fast(zv);
  }
}

// ---------------------------------------------------------------------------
// K5: out = yg @ W_out^T (M=32768, N=64, K=256).
// Same tile structure as k_xz: 64-row output tile, K in 4 chunks of 64, both
// operands staged transposed [k][m] in LDS, 4x4 micro-tile per thread.
// 32 KB LDS -> 5 blocks/CU. All global traffic is coalesced float4.
// Grid MUST be ROWS/64 (64 output rows per block).
// ---------------------------------------------------------------------------
__global__ __launch_bounds__(256) void k_out(const float* __restrict__ yg,
                                             const float* __restrict__ Wout,
                                             float* __restrict__ out) {
  __shared__ float Ys[64][64];  // [k][m]
  __shared__ float Ws[64][64];  // [k][j]
  const int t  = threadIdx.x;
  const int m0 = blockIdx.x * 64;
  const int r  = t >> 2;           // 0..63
  const int kc = (t & 3) * 16;     // k chunk base within 64
  const int tx = t & 15, ty = t >> 4;

  float acc[4][4] = {};
#pragma unroll 1
  for (int kc0 = 0; kc0 < DI; kc0 += 64) {
    const float4* yp = reinterpret_cast<const float4*>(yg   + (m0 + r) * DI + kc0 + kc);
    const float4* wp = reinterpret_cast<const float4*>(Wout + r * DI + kc0 + kc);
#pragma unroll
    for (int i = 0; i < 4; ++i) {
      float4 a = yp[i];
      float4 w = wp[i];
      const int k = kc + i * 4;
      Ys[k + 0][r] = a.x; Ys[k + 1][r] = a.y; Ys[k + 2][r] = a.z; Ys[k + 3][r] = a.w;
      Ws[k + 0][r] = w.x; Ws[k + 1][r] = w.y; Ws[k + 2][r] = w.z; Ws[k + 3][r] = w.w;
    }
    __syncthreads();
#pragma unroll 4
    for (int k = 0; k < 64; ++k) {
      const float4 av = *reinterpret_cast<const float4*>(&Ys[k][ty * 4]);
      const float4 bv = *reinterpret_cast<const float4*>(&Ws[k][tx * 4]);
      const float a[4] = {av.x, av.y, av.z, av.w};
      const float b[4] = {bv.x, bv.y, bv.z, bv.w};
#pragma unroll
      for (int i = 0; i < 4; ++i)
#pragma unroll
        for (int j = 0; j < 4; ++j) acc[i][j] = fmaf(a[i], b[j], acc[i][j]);
    }
    __syncthreads();
  }

#pragma unroll
  for (int i = 0; i < 4; ++i) {
    float4 v = make_float4(acc[i][0], acc[i][1], acc[i][2], acc[i][3]);
    *reinterpret_cast<float4*>(out + (m0 + ty * 4 + i) * DM + tx * 4) = v;
  }
}

// ---------------------------------------------------------------------------
extern "C" void kernel_launch(void* const* d_in, const int* in_sizes, int n_in,
                              void* d_out, int out_size, void* d_ws, size_t ws_size,
                              hipStream_t stream) {
  const float* x    = (const float*)d_in[0];
  const float* Win  = (const float*)d_in[1];
  const float* cw   = (const float*)d_in[2];
  const float* cb   = (const float*)d_in[3];
  const float* Wx   = (const float*)d_in[4];
  const float* Wdt  = (const float*)d_in[5];
  const float* bdt  = (const float*)d_in[6];
  const float* Alog = (const float*)d_in[7];
  const float* Dp   = (const float*)d_in[8];
  const float* Wout = (const float*)d_in[9];
  float* out = (float*)d_out;

  // workspace layout (floats)
  float* ws  = (float*)d_ws;
  float* xs  = ws;                                   // ROWS*DI
  float* z   = xs  + (size_t)ROWS * DI;              // ROWS*DI (later: gated y)
  float* u   = z   + (size_t)ROWS * DI;              // ROWS*DI
  float* dtb = u   + (size_t)ROWS * DI;              // ROWS*DI
  float* Bm  = dtb + (size_t)ROWS * DI;              // ROWS*DS
  float* Cm  = Bm  + (size_t)ROWS * DS;              // ROWS*DS
  float* H   = Cm  + (size_t)ROWS * DS;              // BATCH*NCH*DS*DI
  float* DTS = H   + (size_t)BATCH * NCH * DS * DI;  // BATCH*NCH*DI
  // total ~147.3 MB

  k_xz   <<<dim3(ROWS / 64, 8), 256, 0, stream>>>(x, Win, xs, z);
  k_conv <<<ROWS * DI / 256, 256, 0, stream>>>(xs, cw, cb, u);
  k_dbc  <<<2048, 256, 0, stream>>>(u, Wx, Wdt, bdt, dtb, Bm, Cm);
  k_scanA<<<BATCH * NCH, 256, 0, stream>>>(dtb, u, Bm, Alog, H, DTS);
  k_fix  <<<BATCH * DI * DS / 256, 256, 0, stream>>>(H, DTS, Alog);
  k_scanC<<<BATCH * NCH, 256, 0, stream>>>(dtb, u, z, Bm, Cm, Alog, Dp, H, z);
  k_out  <<<ROWS / 64, 256, 0, stream>>>(z, Wout, out);
}